// Round 5
// baseline (64.912 us; speedup 1.0000x reference)
//
#include <hip/hip_runtime.h>
#include <hip/hip_bf16.h>
#include <math.h>

// Problem sizes (fixed by setup_inputs): B=4096, D=128, K=256, c=1.0
#define B_SZ 4096
#define D_SZ 128
#define K_SZ 256
#define MT   32          // m-tile (batch rows) per block
#define NT   16          // n-tile (k prototypes) per block
#define LSTR 136         // LDS row stride in bf16 elems (272B, 16B-aligned rows)
#define MIN_NORM 1e-15f

typedef __attribute__((ext_vector_type(8))) short  short8;   // MFMA A/B frag (8 bf16)
typedef __attribute__((ext_vector_type(4))) float  floatx4;  // MFMA C/D frag

// 4 f32 -> 4 bf16 (RNE) via packed v_cvt_pk_bf16_f32
static __device__ __forceinline__ ushort4 cvt4(float4 a) {
    union { ushort4 s; __hip_bfloat162 h[2]; } u;
    u.h[0] = __float22bfloat162_rn(make_float2(a.x, a.y));
    u.h[1] = __float22bfloat162_rn(make_float2(a.z, a.w));
    return u.s;
}
static __device__ __forceinline__ float dot4(float4 a, float4 b) {
    return a.x * b.x + a.y * b.y + a.z * b.z + a.w * b.w;
}

// 32x16 output tile per block -> 2048 blocks (~6-8 blocks/CU, 24+ waves/CU).
// Balanced staging: threads 0-127 stage p+a (stats p2/pa/a2 thread-local),
// threads 128-255 stage x (stat x2). 8 float4 loads per thread everywhere.
// ONE barrier; waves 0-1 do MFMA + fused epilogue; waves 2-3 exit.
__global__ __launch_bounds__(256) void mobius_mlr_kernel(
        const float* __restrict__ x, const float* __restrict__ p,
        const float* __restrict__ a, float* __restrict__ out) {
    // (32+16+16) x 136 x 2B = 17408 B tile LDS + stats
    __shared__ __align__(16) unsigned short lx[MT * LSTR];
    __shared__ __align__(16) unsigned short lp[NT * LSTR];
    __shared__ __align__(16) unsigned short la[NT * LSTR];
    __shared__ float xsq[MT];                   // |x_b|^2
    __shared__ float p2s[NT], pas[NT], ans[NT]; // |p|^2, p.a, max(||a||,MIN_NORM)

    const int tid = threadIdx.x;
    const int mb0 = blockIdx.x * MT;
    const int nb0 = blockIdx.y * NT;

    if (tid < 128) {
        // ---- p + a staging & stats: 8 threads/row, 16 floats each ----
        const int row = tid >> 3;        // 0..15
        const int seg = tid & 7;         // 16-float segment
        const float* prow = p + (size_t)(nb0 + row) * D_SZ + seg * 16;
        const float* arow = a + (size_t)(nb0 + row) * D_SZ + seg * 16;
        float4 pv[4], av[4];
        #pragma unroll
        for (int i = 0; i < 4; ++i) pv[i] = *(const float4*)(prow + i * 4);
        #pragma unroll
        for (int i = 0; i < 4; ++i) av[i] = *(const float4*)(arow + i * 4);
        float p2 = 0.f, pa = 0.f, a2 = 0.f;
        #pragma unroll
        for (int i = 0; i < 4; ++i) {
            p2 += dot4(pv[i], pv[i]);
            pa += dot4(pv[i], av[i]);
            a2 += dot4(av[i], av[i]);
            *(ushort4*)&lp[row * LSTR + seg * 16 + i * 4] = cvt4(pv[i]);
            *(ushort4*)&la[row * LSTR + seg * 16 + i * 4] = cvt4(av[i]);
        }
        p2 += __shfl_xor(p2, 1); p2 += __shfl_xor(p2, 2); p2 += __shfl_xor(p2, 4);
        pa += __shfl_xor(pa, 1); pa += __shfl_xor(pa, 2); pa += __shfl_xor(pa, 4);
        a2 += __shfl_xor(a2, 1); a2 += __shfl_xor(a2, 2); a2 += __shfl_xor(a2, 4);
        if (seg == 0) {
            p2s[row] = p2;
            pas[row] = pa;
            ans[row] = fmaxf(sqrtf(a2), MIN_NORM);
        }
    } else {
        // ---- x staging & stats: 4 threads/row, 32 floats each ----
        const int t   = tid - 128;
        const int row = t >> 2;          // 0..31
        const int c   = t & 3;           // 32-float segment
        const float* xrow = x + (size_t)(mb0 + row) * D_SZ + c * 32;
        float4 xv[8];
        #pragma unroll
        for (int i = 0; i < 8; ++i) xv[i] = *(const float4*)(xrow + i * 4);
        float x2 = 0.f;
        #pragma unroll
        for (int i = 0; i < 8; ++i) {
            x2 += dot4(xv[i], xv[i]);
            *(ushort4*)&lx[row * LSTR + c * 32 + i * 4] = cvt4(xv[i]);
        }
        x2 += __shfl_xor(x2, 1); x2 += __shfl_xor(x2, 2);
        if (c == 0) xsq[row] = x2;
    }
    __syncthreads();   // the ONLY barrier

    const int wv = tid >> 6;
    if (wv >= 2) return;                // waves 2-3 done (staging only)

    // ---- MFMA: wave wv computes m-quadrant wv of both GEMMs (16x16 each) ----
    const int lane = tid & 63;
    const int quad = lane >> 4;
    const int r16  = lane & 15;

    floatx4 accp = {0.f, 0.f, 0.f, 0.f};
    floatx4 acca = {0.f, 0.f, 0.f, 0.f};
    #pragma unroll
    for (int dc = 0; dc < 4; ++dc) {
        int d0 = dc * 32 + quad * 8;
        short8 af = *(const short8*)&lx[(wv * 16 + r16) * LSTR + d0];
        short8 bp = *(const short8*)&lp[r16 * LSTR + d0];
        short8 ba = *(const short8*)&la[r16 * LSTR + d0];
        accp = __builtin_amdgcn_mfma_f32_16x16x32_bf16(af, bp, accp, 0, 0, 0);
        acca = __builtin_amdgcn_mfma_f32_16x16x32_bf16(af, ba, acca, 0, 0, 0);
    }

    // ---- fused epilogue ----
    // C/D layout (verified): col = lane&15, row = (lane>>4)*4 + reg
    const float p2v = p2s[r16];
    const float pav = pas[r16];
    const float anv = ans[r16];
    #pragma unroll
    for (int r = 0; r < 4; ++r) {
        int rowl = wv * 16 + quad * 4 + r;
        float x2v = xsq[rowl];
        float pdx = accp[r];        // p_k . x_b   (bf16 MFMA)
        float xda = acca[r];        // x_b . a_k
        // mobius_add(-p, x, c=1): xy = -(p.x), x2 = |p|^2, y2 = |x|^2
        float alpha = 1.0f - 2.0f * pdx + x2v;
        float beta  = 1.0f - p2v;
        float den   = fmaxf(1.0f - 2.0f * pdx + p2v * x2v, MIN_NORM);
        float invd  = __builtin_amdgcn_rcpf(den);
        float sqn   = (alpha * alpha * p2v - 2.0f * alpha * beta * pdx
                       + beta * beta * x2v) * invd * invd;   // |mpx|^2
        sqn = fmaxf(sqn, MIN_NORM);
        float mda  = (beta * xda - alpha * pav) * invd;      // mpx . a
        float dden = fmaxf((1.0f - sqn) * anv, MIN_NORM);
        float z    = 2.0f * mda * __builtin_amdgcn_rcpf(dden);
        float dist = __logf(z + sqrtf(z * z + 1.0f));        // asinh(z), z ~ O(0.02)
        out[(size_t)(mb0 + rowl) * K_SZ + (nb0 + r16)] = 2.0f * anv * dist;
    }
}

extern "C" void kernel_launch(void* const* d_in, const int* in_sizes, int n_in,
                              void* d_out, int out_size, void* d_ws, size_t ws_size,
                              hipStream_t stream) {
    const float* x = (const float*)d_in[0];
    const float* p = (const float*)d_in[1];
    const float* a = (const float*)d_in[2];
    float* out = (float*)d_out;
    dim3 grid(B_SZ / MT, K_SZ / NT);   // (128, 16) = 2048 blocks -> ~6-8 blocks/CU
    mobius_mlr_kernel<<<grid, dim3(256), 0, stream>>>(x, p, a, out);
}

// Round 6
// 63.935 us; speedup vs baseline: 1.0153x; 1.0153x over previous
//
#include <hip/hip_runtime.h>
#include <hip/hip_bf16.h>
#include <math.h>

// Problem sizes (fixed by setup_inputs): B=4096, D=128, K=256, c=1.0
#define B_SZ 4096
#define D_SZ 128
#define K_SZ 256
#define MT   32          // m-tile (batch rows) per block
#define NT   32          // n-tile (k prototypes) per block
#define LSTR 136         // LDS row stride in bf16 elems (272B, 16B-aligned rows)
#define MIN_NORM 1e-15f

// Best measured config (R2/R4 ≈ 63.4-63.7 µs bench): 1024 blocks = 4 blocks/CU,
// 32x32 tile, coalesced f32->bf16 LDS staging with f32 stats fused into the
// load pass, ONE barrier, 4 waves x 8 MFMA, fused asinh epilogue.
// Measured alternatives: 2048 blocks/32x16 = +1.2us; no-LDS gather = +5.9us;
// 256 blocks/64x64 = +3.6us. HBM bytes are at the problem minimum (~6.3 MB).

typedef __attribute__((ext_vector_type(8))) short  short8;   // MFMA A/B frag (8 bf16)
typedef __attribute__((ext_vector_type(4))) float  floatx4;  // MFMA C/D frag

// 4 f32 -> 4 bf16 (RNE) via packed v_cvt_pk_bf16_f32
static __device__ __forceinline__ ushort4 cvt4(float4 a) {
    union { ushort4 s; __hip_bfloat162 h[2]; } u;
    u.h[0] = __float22bfloat162_rn(make_float2(a.x, a.y));
    u.h[1] = __float22bfloat162_rn(make_float2(a.z, a.w));
    return u.s;
}
static __device__ __forceinline__ float dot4(float4 a, float4 b) {
    return a.x * b.x + a.y * b.y + a.z * b.z + a.w * b.w;
}

__global__ __launch_bounds__(256) void mobius_mlr_kernel(
        const float* __restrict__ x, const float* __restrict__ p,
        const float* __restrict__ a, float* __restrict__ out) {
    // 3 x (32 x 136 x 2B) = 26112 B tile LDS + stat arrays
    __shared__ __align__(16) unsigned short lx[MT * LSTR];
    __shared__ __align__(16) unsigned short lp[NT * LSTR];
    __shared__ __align__(16) unsigned short la[NT * LSTR];
    __shared__ float xsq[MT];                   // |x_b|^2
    __shared__ float p2s[NT], pas[NT], ans[NT]; // |p|^2, p.a, max(||a||,MIN_NORM)

    const int tid = threadIdx.x;
    const int mb0 = blockIdx.x * MT;
    const int nb0 = blockIdx.y * NT;

    // ---- staging + stats in one pass: 8 threads per row, 64B (4xfloat4) each ----
    const int row = tid >> 3;        // 0..31
    const int seg = tid & 7;         // 0..7 -> 16-float segment
    const float* xrow = x + (size_t)(mb0 + row) * D_SZ + seg * 16;
    const float* prow = p + (size_t)(nb0 + row) * D_SZ + seg * 16;
    const float* arow = a + (size_t)(nb0 + row) * D_SZ + seg * 16;

    float4 xv[4], pv[4], av[4];
    #pragma unroll
    for (int i = 0; i < 4; ++i) xv[i] = *(const float4*)(xrow + i * 4);
    #pragma unroll
    for (int i = 0; i < 4; ++i) pv[i] = *(const float4*)(prow + i * 4);
    #pragma unroll
    for (int i = 0; i < 4; ++i) av[i] = *(const float4*)(arow + i * 4);

    float x2 = 0.f, p2 = 0.f, pa = 0.f, a2 = 0.f;
    #pragma unroll
    for (int i = 0; i < 4; ++i) {
        x2 += dot4(xv[i], xv[i]);
        p2 += dot4(pv[i], pv[i]);
        pa += dot4(pv[i], av[i]);
        a2 += dot4(av[i], av[i]);
        *(ushort4*)&lx[row * LSTR + seg * 16 + i * 4] = cvt4(xv[i]);
        *(ushort4*)&lp[row * LSTR + seg * 16 + i * 4] = cvt4(pv[i]);
        *(ushort4*)&la[row * LSTR + seg * 16 + i * 4] = cvt4(av[i]);
    }
    // reduce across the 8 segment-lanes of this row (same wave: xor < 8)
    x2 += __shfl_xor(x2, 1); x2 += __shfl_xor(x2, 2); x2 += __shfl_xor(x2, 4);
    p2 += __shfl_xor(p2, 1); p2 += __shfl_xor(p2, 2); p2 += __shfl_xor(p2, 4);
    pa += __shfl_xor(pa, 1); pa += __shfl_xor(pa, 2); pa += __shfl_xor(pa, 4);
    a2 += __shfl_xor(a2, 1); a2 += __shfl_xor(a2, 2); a2 += __shfl_xor(a2, 4);
    if (seg == 0) {
        xsq[row] = x2;
        p2s[row] = p2;
        pas[row] = pa;
        ans[row] = fmaxf(sqrtf(a2), MIN_NORM);
    }
    __syncthreads();   // the ONLY barrier

    // ---- MFMA: each wave computes one 16x16 quadrant of both GEMMs ----
    const int lane = tid & 63;
    const int wv   = tid >> 6;
    const int mi   = wv & 1;            // m-quadrant
    const int ni   = wv >> 1;           // n-quadrant
    const int quad = lane >> 4;
    const int r16  = lane & 15;

    floatx4 accp = {0.f, 0.f, 0.f, 0.f};
    floatx4 acca = {0.f, 0.f, 0.f, 0.f};
    #pragma unroll
    for (int dc = 0; dc < 4; ++dc) {
        int d0 = dc * 32 + quad * 8;
        short8 af = *(const short8*)&lx[(mi * 16 + r16) * LSTR + d0];
        short8 bp = *(const short8*)&lp[(ni * 16 + r16) * LSTR + d0];
        short8 ba = *(const short8*)&la[(ni * 16 + r16) * LSTR + d0];
        accp = __builtin_amdgcn_mfma_f32_16x16x32_bf16(af, bp, accp, 0, 0, 0);
        acca = __builtin_amdgcn_mfma_f32_16x16x32_bf16(af, ba, acca, 0, 0, 0);
    }

    // ---- fused epilogue ----
    // C/D layout (verified): col = lane&15, row = (lane>>4)*4 + reg
    const int coll = ni * 16 + r16;
    const float p2v = p2s[coll];
    const float pav = pas[coll];
    const float anv = ans[coll];
    #pragma unroll
    for (int r = 0; r < 4; ++r) {
        int rowl = mi * 16 + quad * 4 + r;
        float x2v = xsq[rowl];
        float pdx = accp[r];        // p_k . x_b   (bf16 MFMA)
        float xda = acca[r];        // x_b . a_k
        // mobius_add(-p, x, c=1): xy = -(p.x), x2 = |p|^2, y2 = |x|^2
        float alpha = 1.0f - 2.0f * pdx + x2v;
        float beta  = 1.0f - p2v;
        float den   = fmaxf(1.0f - 2.0f * pdx + p2v * x2v, MIN_NORM);
        float invd  = __builtin_amdgcn_rcpf(den);
        float sqn   = (alpha * alpha * p2v - 2.0f * alpha * beta * pdx
                       + beta * beta * x2v) * invd * invd;   // |mpx|^2
        sqn = fmaxf(sqn, MIN_NORM);
        float mda  = (beta * xda - alpha * pav) * invd;      // mpx . a
        float dden = fmaxf((1.0f - sqn) * anv, MIN_NORM);
        float z    = 2.0f * mda * __builtin_amdgcn_rcpf(dden);
        float dist = __logf(z + sqrtf(z * z + 1.0f));        // asinh(z), z ~ O(0.02)
        out[(size_t)(mb0 + rowl) * K_SZ + (nb0 + coll)] = 2.0f * anv * dist;
    }
}

extern "C" void kernel_launch(void* const* d_in, const int* in_sizes, int n_in,
                              void* d_out, int out_size, void* d_ws, size_t ws_size,
                              hipStream_t stream) {
    const float* x = (const float*)d_in[0];
    const float* p = (const float*)d_in[1];
    const float* a = (const float*)d_in[2];
    float* out = (float*)d_out;
    dim3 grid(B_SZ / MT, K_SZ / NT);   // (128, 8) = 1024 blocks -> 4 blocks/CU
    mobius_mlr_kernel<<<grid, dim3(256), 0, stream>>>(x, p, a, out);
}